// Round 5
// baseline (258.214 us; speedup 1.0000x reference)
//
#include <hip/hip_runtime.h>
#include <hip/hip_bf16.h>
#include <stdint.h>

#define BB 32768
#define NN 512
#define CGIT 7
#define NCG 16
#define NPART 64
#define NTILE 10

typedef __attribute__((ext_vector_type(8))) short bf16x8;
typedef __attribute__((ext_vector_type(4))) float f32x4;

__device__ __forceinline__ void gld_lds16(const void* g, void* l) {
  typedef __attribute__((address_space(1))) const unsigned int gas_u32;
  typedef __attribute__((address_space(3))) unsigned int las_u32;
  __builtin_amdgcn_global_load_lds((gas_u32*)(uintptr_t)g,
                                   (las_u32*)(uint32_t)(uintptr_t)l, 16, 0, 0);
}

__device__ __forceinline__ unsigned short f2bf(float x) {
  __hip_bfloat16 h = __float2bfloat16(x);
  return *reinterpret_cast<unsigned short*>(&h);
}

__device__ __forceinline__ float bf2f(unsigned short u) {
  return __uint_as_float(((unsigned)u) << 16);
}

__device__ __forceinline__ float wave_reduce(float v) {
#pragma unroll
  for (int off = 32; off > 0; off >>= 1) v += __shfl_xor(v, off, 64);
  return v;
}

__device__ __forceinline__ float block_reduce(float v, float* red, int nw) {
  v = wave_reduce(v);
  const int wv = threadIdx.x >> 6, ln = threadIdx.x & 63;
  if (ln == 0) red[wv] = v;
  __syncthreads();
  if (threadIdx.x == 0) {
    float a = 0;
    for (int i = 0; i < nw; ++i) a += red[i];
    red[15] = a;
  }
  __syncthreads();
  return red[15];
}

// 16-block device-scope barrier (monotone epoch counter, no reset).
__device__ __forceinline__ void cg_barrier(int* ctr, int target) {
  __threadfence();
  __syncthreads();
  if (threadIdx.x == 0) {
    __hip_atomic_fetch_add(ctr, 1, __ATOMIC_ACQ_REL, __HIP_MEMORY_SCOPE_AGENT);
    while (__hip_atomic_load(ctr, __ATOMIC_ACQUIRE, __HIP_MEMORY_SCOPE_AGENT) < target)
      __builtin_amdgcn_s_sleep(16);
  }
  __syncthreads();
}

// K1: blocks 0..15: replicated 16-block CG on Gamma v = SR (fp32, 7 iters), hidden
//     under the worker phase. blocks 16..1039: r = exp(sigma-lsh) -> bf16
//     transposed Rt[N][B] + colsum buckets.
__global__ __launch_bounds__(512) void k1_rexp(
    const float* __restrict__ lsh, const float* __restrict__ sig,
    const float* __restrict__ SR, const float* __restrict__ Gamma,
    unsigned short* __restrict__ Rt, float* __restrict__ colsum,
    float* __restrict__ Ap, int* __restrict__ ctr, float* __restrict__ v) {
  __shared__ __align__(16) float sm[3328];
  const int t = threadIdx.x;
  if (blockIdx.x < NCG) {
    // ---- replicated CG ----
    float* sp = sm;          // p vector (full, replicated)
    float* red = sm + 512;   // 16 floats
    const int b = blockIdx.x;
    const int lane = t & 63, wv = t >> 6;
    const int rlo = b * 32;
    float s = SR[t];
    float x = 0.f, r = s;
    sp[t] = s;
    float rr = block_reduce(s * s, red, 8);
    for (int it = 0; it < CGIT; ++it) {
      float* apg = Ap + (it & 1) * 512;
      // matvec for own 32 rows (rows rlo+4*wv..+3), row-major coalesced
#pragma unroll
      for (int rw = 0; rw < 4; ++rw) {
        const int row = rlo + 4 * wv + rw;
        const float4* g = (const float4*)(Gamma + (size_t)row * NN);
        float4 g0 = g[lane], g1 = g[lane + 64];
        float4 p0 = *(const float4*)&sp[4 * lane];
        float4 p1 = *(const float4*)&sp[4 * lane + 256];
        float d = g0.x * p0.x + g0.y * p0.y + g0.z * p0.z + g0.w * p0.w +
                  g1.x * p1.x + g1.y * p1.y + g1.z * p1.z + g1.w * p1.w;
        d = wave_reduce(d);
        if (lane == 0) apg[row] = d;
      }
      cg_barrier(ctr, NCG * (it + 1));
      const float ap = apg[t];
      float pAp = block_reduce(sp[t] * ap, red, 8);
      float alpha = rr / pAp;
      x += alpha * sp[t];
      r -= alpha * ap;
      float rrn = block_reduce(r * r, red, 8);
      float beta = rrn / rr;
      rr = rrn;
      float pn = r + beta * sp[t];
      __syncthreads();
      sp[t] = pn;
      __syncthreads();
    }
    if (b == 0) v[t] = x;
    return;
  }
  // ---- worker: transpose+exp ----
  unsigned short* tile = (unsigned short*)sm;  // [64 j][36 b]
  float* scr = sm + 1152;                      // [32][68]
  const int tc = t & 15, tg = t >> 4;
  const int wb = blockIdx.x - NCG;
  const int bb = wb * 32;
  const int jl = t >> 3, bc = (t & 7) * 4;
  const size_t rowbase = (size_t)(bb + tg) * NN + 4 * tc;
  float4 sv = *(const float4*)(sig + rowbase);
  float4 lv = *(const float4*)(lsh + rowbase);
  for (int jt = 0; jt < 8; ++jt) {
    const int j0 = jt * 64;
    float r0 = __expf(sv.x - lv.x), r1 = __expf(sv.y - lv.y);
    float r2 = __expf(sv.z - lv.z), r3 = __expf(sv.w - lv.w);
    if (jt < 7) {  // prefetch next chunk before the barrier
      sv = *(const float4*)(sig + rowbase + 64 * (jt + 1));
      lv = *(const float4*)(lsh + rowbase + 64 * (jt + 1));
    }
    scr[tg * 68 + 4 * tc + 0] = r0;
    scr[tg * 68 + 4 * tc + 1] = r1;
    scr[tg * 68 + 4 * tc + 2] = r2;
    scr[tg * 68 + 4 * tc + 3] = r3;
    tile[(4 * tc + 0) * 36 + tg] = f2bf(r0);
    tile[(4 * tc + 1) * 36 + tg] = f2bf(r1);
    tile[(4 * tc + 2) * 36 + tg] = f2bf(r2);
    tile[(4 * tc + 3) * 36 + tg] = f2bf(r3);
    __syncthreads();
    {
      ushort4 vv = *(const ushort4*)(tile + jl * 36 + bc);
      *(ushort4*)(Rt + (size_t)(j0 + jl) * BB + bb + bc) = vv;
    }
    if (t < 64) {
      float sacc = 0;
#pragma unroll
      for (int g = 0; g < 32; ++g) sacc += scr[g * 68 + t];
      atomicAdd(&colsum[(wb & 7) * NN + j0 + t], sacc);
    }
    __syncthreads();
  }
}

// K2: Cpart[kc](bf16) = Rt_i * Rt_j^T over 512-wide K-chunk, upper-triangle tiles
//     (off-diag epilogue writes both C and C^T).
__global__ __launch_bounds__(512) void k2_syrk(
    const unsigned short* __restrict__ Rt, unsigned short* __restrict__ Cpart) {
  __shared__ __align__(16) unsigned short smem[16384];  // As[128][64], Bs[128][64]
  const int wb = blockIdx.x;
  const int kc = wb / NTILE, tt = wb % NTILE;
  const int ti = (int)((0x3221110000ULL >> (4 * tt)) & 0xF);
  const int tj = (int)((0x3323213210ULL >> (4 * tt)) & 0xF);
  const int i0 = ti * 128, j0 = tj * 128;
  const int diag = (ti == tj);
  const size_t b0 = (size_t)kc * 512;
  const int t = threadIdx.x, lane = t & 63, wv = t >> 6;
  const int wi = (wv & 3) * 32, wj = (wv >> 2) * 64;
  const int lm = lane & 15, lq = lane >> 4;
  unsigned short* As = smem;
  unsigned short* Bs = diag ? smem : smem + 8192;
  const int srow = t >> 3, scol = (t & 7) * 8;
  f32x4 acc[2][4];
#pragma unroll
  for (int a = 0; a < 2; ++a)
#pragma unroll
    for (int b = 0; b < 4; ++b) acc[a][b] = (f32x4){0.f, 0.f, 0.f, 0.f};

  for (int ks = 0; ks < 8; ++ks) {
    const size_t bcur = b0 + ks * 64;
    gld_lds16(Rt + (size_t)(i0 + srow) * BB + bcur + scol, As + srow * 64 + scol);
    gld_lds16(Rt + (size_t)(i0 + 64 + srow) * BB + bcur + scol, As + (64 + srow) * 64 + scol);
    if (!diag) {
      gld_lds16(Rt + (size_t)(j0 + srow) * BB + bcur + scol, Bs + srow * 64 + scol);
      gld_lds16(Rt + (size_t)(j0 + 64 + srow) * BB + bcur + scol, Bs + (64 + srow) * 64 + scol);
    }
    __syncthreads();
#pragma unroll
    for (int s = 0; s < 2; ++s) {
      bf16x8 af[2], bfr[4];
#pragma unroll
      for (int g = 0; g < 2; ++g)
        af[g] = *(const bf16x8*)(As + (wi + g * 16 + lm) * 64 + s * 32 + lq * 8);
#pragma unroll
      for (int g = 0; g < 4; ++g)
        bfr[g] = *(const bf16x8*)(Bs + (wj + g * 16 + lm) * 64 + s * 32 + lq * 8);
#pragma unroll
      for (int gm = 0; gm < 2; ++gm)
#pragma unroll
        for (int gn = 0; gn < 4; ++gn)
          acc[gm][gn] = __builtin_amdgcn_mfma_f32_16x16x32_bf16(af[gm], bfr[gn], acc[gm][gn], 0, 0, 0);
    }
    __syncthreads();
  }
  // C/D layout: col = lane&15, row = (lane>>4)*4 + reg
  unsigned short* Cw = Cpart + (size_t)kc * NN * NN;
#pragma unroll
  for (int gm = 0; gm < 2; ++gm) {
    const int rbase = i0 + wi + gm * 16 + lq * 4;
#pragma unroll
    for (int gn = 0; gn < 4; ++gn) {
      const int col = j0 + wj + gn * 16 + lm;
      unsigned short e0 = f2bf(acc[gm][gn][0]), e1 = f2bf(acc[gm][gn][1]);
      unsigned short e2 = f2bf(acc[gm][gn][2]), e3 = f2bf(acc[gm][gn][3]);
      Cw[(size_t)(rbase + 0) * NN + col] = e0;
      Cw[(size_t)(rbase + 1) * NN + col] = e1;
      Cw[(size_t)(rbase + 2) * NN + col] = e2;
      Cw[(size_t)(rbase + 3) * NN + col] = e3;
      if (!diag)
        *(ushort4*)(Cw + (size_t)col * NN + rbase) = make_ushort4(e0, e1, e2, e3);
    }
  }
}

// K3: secondsum = sum_ij v_i Gamma_ij v_j (sum_p Cpart[p][i][j]); last block folds
//     the final loss (merged K4).
__global__ __launch_bounds__(256) void k3_contract(
    const float* __restrict__ Gamma, const unsigned short* __restrict__ Cpart,
    const float* __restrict__ v, const float* __restrict__ colsum,
    const float* __restrict__ SR, const int* __restrict__ kp,
    float* __restrict__ secsum, int* __restrict__ done, float* __restrict__ out) {
  __shared__ float red[4];
  __shared__ int amlast;
  const int t = threadIdx.x;
  const size_t e = ((size_t)blockIdx.x * 256 + t) * 4;
  const int j = (int)(e & 511), i = (int)(e >> 9);
  float cx = 0, cy = 0, cz = 0, cw = 0;
  for (int pp = 0; pp < NPART; ++pp) {
    ushort4 u = *(const ushort4*)(Cpart + (size_t)pp * NN * NN + e);
    cx += bf2f(u.x); cy += bf2f(u.y); cz += bf2f(u.z); cw += bf2f(u.w);
  }
  float4 g = *(const float4*)(Gamma + e);
  float4 vj = *(const float4*)(v + j);
  float vi = v[i];
  float p = vi * (g.x * cx * vj.x + g.y * cy * vj.y + g.z * cz * vj.z + g.w * cw * vj.w);
  p = wave_reduce(p);
  if ((t & 63) == 0) red[t >> 6] = p;
  __syncthreads();
  if (t == 0) {
    atomicAdd(secsum, red[0] + red[1] + red[2] + red[3]);
    __threadfence();
    int tk = __hip_atomic_fetch_add(done, 1, __ATOMIC_ACQ_REL, __HIP_MEMORY_SCOPE_AGENT);
    amlast = (tk == (int)gridDim.x - 1);
  }
  __syncthreads();
  if (!amlast) return;
  // final fold (256 threads)
  float fpart = 0;
  for (int jj = t; jj < NN; jj += 256) {
    float cs = 0;
#pragma unroll
    for (int bk = 0; bk < 8; ++bk) cs += colsum[bk * NN + jj];
    fpart += (cs * (1.0f / BB)) * v[jj] * SR[jj];
  }
  fpart = wave_reduce(fpart);
  __syncthreads();
  if ((t & 63) == 0) red[t >> 6] = fpart;
  __syncthreads();
  if (t == 0) {
    float first = red[0] + red[1] + red[2] + red[3];
    float kk = (float)kp[0];
    float sec = __hip_atomic_load(secsum, __ATOMIC_ACQUIRE, __HIP_MEMORY_SCOPE_AGENT);
    out[0] = -(first / kk - sec / ((float)BB * 2.0f * kk));
  }
}

extern "C" void kernel_launch(void* const* d_in, const int* in_sizes, int n_in,
                              void* d_out, int out_size, void* d_ws, size_t ws_size,
                              hipStream_t stream) {
  const float* lsh = (const float*)d_in[0];
  const float* sig = (const float*)d_in[1];
  const float* SR = (const float*)d_in[2];
  const float* Gam = (const float*)d_in[3];
  const int* kp = (const int*)d_in[4];
  char* ws = (char*)d_ws;
  // layout: Cpart bf16 32MB | small (zeroed) 23KB | Rt 32MB
  unsigned short* Cpart = (unsigned short*)ws;
  const size_t coff = (size_t)NPART * NN * NN * sizeof(unsigned short);  // 32 MB
  float* F = (float*)(ws + coff);
  float* colsum = F;              // [4096]
  float* secsum = F + 4096;       // [1]
  int* done = (int*)(F + 4100);   // [1]
  int* ctr = (int*)(F + 4104);    // [1]
  float* Ap = F + 4160;           // [2][512]
  float* v = F + 5248;            // [512]
  unsigned short* Rt = (unsigned short*)(ws + coff + 32768);  // 32 MB

  hipMemsetAsync(F, 0, 5760 * sizeof(float), stream);
  k1_rexp<<<1024 + NCG, 512, 0, stream>>>(lsh, sig, SR, Gam, Rt, colsum, Ap, ctr, v);
  k2_syrk<<<NPART * NTILE, 512, 0, stream>>>(Rt, Cpart);
  k3_contract<<<256, 256, 0, stream>>>(Gam, Cpart, v, colsum, SR, kp, secsum, done, (float*)d_out);
}